// Round 1
// baseline (254.327 us; speedup 1.0000x reference)
//
#include <hip/hip_runtime.h>
#include <hip/hip_bf16.h>

// SparsePropMaxPool: map_h[b,h,s,e] = max(x[b,h,s..e]) at "active" (s,e)
// positions, 0 elsewhere; map_mask[b,0,s,e] = active ? 1 : 0.
//
// Active predicate (d = e - s >= 0), derived from NUM_SCALE_LAYERS=[16,8,8]:
//   scale 0: d in [0,15], any s
//   scale 1: d in {17,19,...,31} (odd), s even
//   scale 2: d in {35,39,...,63} (d%4==3), s%4==0
//
// B=32, H=512, N=64 fixed by the reference setup.

#define BB 32
#define HH 512
#define NN 64

__device__ __forceinline__ unsigned long long active_mask_for_e(int e) {
    // Bit s set <=> (s, e) is an active position.
    unsigned long long m;
    // band 1: s in [e-15, e]  (d in [0,15])
    if (e >= 15) m = 0xFFFFull << (e - 15);
    else         m = 0xFFFFull >> (15 - e);
    // band 2: d odd in [17,31], s even  => only when e is odd
    if ((e & 1) && e >= 17) {
        int a = e - 31; if (a < 0) a = 0;
        int b = e - 17;
        unsigned long long r = (~0ull >> (63 - b)) & (~0ull << a);
        m |= r & 0x5555555555555555ull;
    }
    // band 3: d%4==3 in [35,63], s%4==0 => only when e%4==3
    if (((e & 3) == 3) && e >= 35) {
        int b = e - 35;
        unsigned long long r = (~0ull >> (63 - b));
        m |= r & 0x1111111111111111ull;
    }
    return m;
}

__global__ __launch_bounds__(256) void sppool_map_kernel(
        const float* __restrict__ x, float* __restrict__ map_h) {
    __shared__ float xs[16][65];              // +1 pad: conflict-free row reads
    const int tid  = threadIdx.x;
    const int lrow = tid >> 4;                // 0..15 local row
    const int e0   = (tid & 15) << 2;         // this thread's 4 e-values
    const size_t rowbase = (size_t)blockIdx.x * 16;

    // cooperative load: 16 rows x 64 floats
    const float* xin = x + rowbase * NN;
    for (int i = tid; i < 16 * NN; i += 256)
        xs[i >> 6][i & 63] = xin[i];
    __syncthreads();

    const float* xr = xs[lrow];
    const unsigned long long am0 = active_mask_for_e(e0 + 0);
    const unsigned long long am1 = active_mask_for_e(e0 + 1);
    const unsigned long long am2 = active_mask_for_e(e0 + 2);
    const unsigned long long am3 = active_mask_for_e(e0 + 3);

    float m0 = -INFINITY, m1 = -INFINITY, m2 = -INFINITY, m3 = -INFINITY;
    float* out = map_h + (rowbase + lrow) * (NN * NN) + e0;

    #pragma unroll 8
    for (int s = 63; s >= 0; --s) {
        const float xv = xr[s];
        // running suffix max per e (only once s enters the window)
        m0 = fmaxf(m0, (s <= e0 + 0) ? xv : -INFINITY);
        m1 = fmaxf(m1, (s <= e0 + 1) ? xv : -INFINITY);
        m2 = fmaxf(m2, (s <= e0 + 2) ? xv : -INFINITY);
        m3 = fmaxf(m3, (s <= e0 + 3) ? xv : -INFINITY);
        float4 v;
        v.x = ((am0 >> s) & 1ull) ? m0 : 0.0f;
        v.y = ((am1 >> s) & 1ull) ? m1 : 0.0f;
        v.z = ((am2 >> s) & 1ull) ? m2 : 0.0f;
        v.w = ((am3 >> s) & 1ull) ? m3 : 0.0f;
        *(float4*)(out + (size_t)s * NN) = v;   // wave: 4 x 256B contiguous
    }
}

__global__ __launch_bounds__(256) void sppool_mask_kernel(
        float* __restrict__ mask_out) {
    // mask: B x 1 x 64 x 64 = 131072 floats = 32768 float4s
    const int idx = blockIdx.x * 256 + threadIdx.x;
    if (idx >= BB * NN * NN / 4) return;
    const int e0 = (idx & 15) << 2;
    const int s  = (idx >> 4) & 63;
    float4 v;
    v.x = ((active_mask_for_e(e0 + 0) >> s) & 1ull) ? 1.0f : 0.0f;
    v.y = ((active_mask_for_e(e0 + 1) >> s) & 1ull) ? 1.0f : 0.0f;
    v.z = ((active_mask_for_e(e0 + 2) >> s) & 1ull) ? 1.0f : 0.0f;
    v.w = ((active_mask_for_e(e0 + 3) >> s) & 1ull) ? 1.0f : 0.0f;
    ((float4*)mask_out)[idx] = v;
}

extern "C" void kernel_launch(void* const* d_in, const int* in_sizes, int n_in,
                              void* d_out, int out_size, void* d_ws, size_t ws_size,
                              hipStream_t stream) {
    const float* x = (const float*)d_in[0];
    float* map_h   = (float*)d_out;
    float* map_mask = (float*)d_out + (size_t)BB * HH * NN * NN;

    // 16384 rows / 16 rows per block
    sppool_map_kernel<<<BB * HH / 16, 256, 0, stream>>>(x, map_h);
    sppool_mask_kernel<<<(BB * NN * NN / 4 + 255) / 256, 256, 0, stream>>>(map_mask);
}